// Round 11
// baseline (447.658 us; speedup 1.0000x reference)
//
#include <hip/hip_runtime.h>

constexpr int NN = 100000;   // nodes
constexpr int NE = 1600000;  // edges
constexpr int DI = 256, DH = 128, DO = 40;

// [R17] 1-level CSR build: 100k dst counters fit in 400KB (L2-resident), so the
// 2-level bucket sort (hist391 -> scan -> bucket-scatter(epack) -> in-bucket sort)
// is replaced by: zero cnt -> global-atomic hist -> scan(98 blk) -> atomic-cursor
// scatter straight into esrc. Deletes the sort kernel + epack (12.8MB R/W).
// esrc writes cluster per-node (deg~16 x 4B = one 64B line).
// [R15 FAILED: merging chain+gemm1 into one kernel paid max(LDS) across branches ->
//  occupancy collapse, +22us. R16: 3-way agg1 split cost +10us (launch drains/tails);
//  top-5 is pinned by the harness's 400MB workspace re-poison fill (59.8us, 87% HBM,
//  uncontrollable) which hides everything 23..58us. No kernel of ours exceeds ~58us
//  except agg1.]
constexpr int WPACK_BLOCKS = 152;              // 128 (W1) + 24 (W2)
constexpr int ZERO_BLOCKS = (NN + 255) / 256;  // 391 (cnt zeroing)
constexpr int NBS2 = (NN + 1023) / 1024;       // 98 scan blocks (NN%4==0, int4-safe)
constexpr int GEMM1_BLOCKS = (NN + 63) / 64;   // 1563
constexpr int HIST_BLOCKS = 1024;
constexpr int SCAT_BLOCKS = 1024;

typedef __attribute__((ext_vector_type(8))) __bf16 bf16x8;
typedef __attribute__((ext_vector_type(4))) float f32x4;

__device__ inline float4 bf4_to_f4(ushort4 u) {
    return make_float4(__builtin_bit_cast(float, (unsigned)u.x << 16),
                       __builtin_bit_cast(float, (unsigned)u.y << 16),
                       __builtin_bit_cast(float, (unsigned)u.z << 16),
                       __builtin_bit_cast(float, (unsigned)u.w << 16));
}
__device__ inline unsigned short f2bf(float f) {
    return __builtin_bit_cast(unsigned short, (__bf16)f);   // RNE
}
__device__ inline bf16x8 bf16x8_zero() {
    bf16x8 r;
    #pragma unroll
    for (int j = 0; j < 8; ++j) r[j] = (__bf16)0.f;
    return r;
}
__device__ inline bf16x8 load_cvt_a(const float* __restrict__ p, bool ok) {
    if (!ok) return bf16x8_zero();
    bf16x8 r;
    const float4 v0 = *(const float4*)p;
    const float4 v1 = *(const float4*)(p + 4);
    r[0] = (__bf16)v0.x; r[1] = (__bf16)v0.y; r[2] = (__bf16)v0.z; r[3] = (__bf16)v0.w;
    r[4] = (__bf16)v1.x; r[5] = (__bf16)v1.y; r[6] = (__bf16)v1.z; r[7] = (__bf16)v1.w;
    return r;
}
__device__ inline void acc4(float4& a, float4 v) {
    a.x += v.x; a.y += v.y; a.z += v.z; a.w += v.w;
}

// ---------------- K1: wpack (blocks 0..151)  ||  zero cnt + off[NN] (152..542) -------
__global__ __launch_bounds__(256) void wpack_zero_kernel(const float* __restrict__ W1,
                                                         const float* __restrict__ W2,
                                                         __bf16* __restrict__ Wf,
                                                         __bf16* __restrict__ Wf2,
                                                         int* __restrict__ cnt,
                                                         int* __restrict__ off) {
    if (blockIdx.x < 128) {
        const int i = blockIdx.x * 256 + threadIdx.x;   // 32768 total
        const int j = i & 7;
        const int lane = (i >> 3) & 63;
        const int nt = (i >> 9) & 7;
        const int kt = i >> 12;
        const int k = kt * 32 + (lane >> 4) * 8 + j;
        const int n = nt * 16 + (lane & 15);
        Wf[i] = (__bf16)W1[(size_t)k * DH + n];
    } else if (blockIdx.x < WPACK_BLOCKS) {
        const int i = (blockIdx.x - 128) * 256 + threadIdx.x;   // 6144 total
        if (i < 6144) {
            const int j = i & 7;
            const int lane = (i >> 3) & 63;
            const int g = i >> 9;          // 0..11
            const int nt = g % 3, ks = g / 3;
            const int k = ks * 32 + (lane >> 4) * 8 + j;
            const int n = nt * 16 + (lane & 15);
            Wf2[i] = (n < DO) ? (__bf16)W2[(size_t)k * DO + n] : (__bf16)0.f;
        }
    } else {
        const int i = (blockIdx.x - WPACK_BLOCKS) * 256 + threadIdx.x;
        if (i < NN) cnt[i] = 0;
        else if (i == NN) off[NN] = NE;    // constant by construction
    }
}

// ---------------- K2: hist — global atomics on per-dst counters (L2-resident) -------
__global__ __launch_bounds__(256) void hist_kernel(const int* __restrict__ dst,
                                                   int* __restrict__ cnt) {
    const int stride = HIST_BLOCKS * 256;
    for (int i = blockIdx.x * 256 + threadIdx.x; i < NE / 4; i += stride) {
        const int4 d = ((const int4*)dst)[i];
        atomicAdd(&cnt[d.x], 1);
        atomicAdd(&cnt[d.y], 1);
        atomicAdd(&cnt[d.z], 1);
        atomicAdd(&cnt[d.w], 1);
    }
}

// ---------------- K3: scan (blocks 0..NBS2-1)  ||  gemm1 (NBS2..NBS2+1562) -----
// [R14] Scan blocks FIRST (scan-last made a +20us serial tail behind gemm1).
// [R14] Wf staged in LDS: gemm1 was latency-bound (MfmaUtil 2.9%, VALU 4.3%,
// occ 33%) streaming the 64KB Wf table from L2 per wave (L1-thrash, ~200cy/load).
// b-fragments come from ds_read_b128. 82us -> below visibility (<58us).
__global__ __launch_bounds__(256) void gemm1_scan_kernel(const float* __restrict__ x,
                                                         const __bf16* __restrict__ Wf,
                                                         __bf16* __restrict__ h1,
                                                         const int* __restrict__ cnt,
                                                         int* __restrict__ off,
                                                         int* __restrict__ cur) {
    __shared__ __bf16 wlds[32768];   // 64 KB: Wf copy (gemm1) / scan scratch (scan)
    if (blockIdx.x >= NBS2) {
        const int t = threadIdx.x;
        const int wave = t >> 6, lane = t & 63;
        const int q = lane >> 4, m = lane & 15;
        const int row0 = (blockIdx.x - NBS2) * 64 + wave * 16;
        const int r = row0 + m;
        const bool ok = r < NN;
        const float* xp = x + (size_t)r * DI;

        bf16x8 a[8];
        #pragma unroll
        for (int kt = 0; kt < 8; ++kt)
            a[kt] = load_cvt_a(xp + kt * 32 + q * 8, ok);

        // Stage Wf (64 KB) into LDS: 16 coalesced 4KB steps.
        bf16x8* wl = (bf16x8*)wlds;
        const bf16x8* wfv = (const bf16x8*)Wf;
        #pragma unroll
        for (int i = 0; i < 16; ++i)
            wl[t + i * 256] = wfv[t + i * 256];

        f32x4 acc[8];
        #pragma unroll
        for (int nt = 0; nt < 8; ++nt)
            #pragma unroll
            for (int rr = 0; rr < 4; ++rr) acc[nt][rr] = 0.f;

        __syncthreads();

        #pragma unroll
        for (int kt = 0; kt < 8; ++kt) {
            #pragma unroll
            for (int nt = 0; nt < 8; ++nt) {
                const bf16x8 b = wl[(kt * 8 + nt) * 64 + lane];   // ds_read_b128
                acc[nt] = __builtin_amdgcn_mfma_f32_16x16x32_bf16(a[kt], b, acc[nt], 0, 0, 0);
            }
        }
        #pragma unroll
        for (int reg = 0; reg < 4; ++reg) {
            const int rr = row0 + q * 4 + reg;
            if (rr < NN) {
                __bf16* hp = h1 + (size_t)rr * DH + m;
                #pragma unroll
                for (int nt = 0; nt < 8; ++nt) hp[nt * 16] = (__bf16)acc[nt][reg];
            }
        }
    } else {
        int* red = (int*)wlds;                      // overlay scan scratch in LDS
        const int b = blockIdx.x;                   // 0..NBS2-1
        const int t = threadIdx.x;
        // prefix base = sum of cnt[0 .. b*1024)  (redundant, L2-fast)
        int s = 0;
        const int limit = b * 1024;
        for (int i = t * 4; i < limit; i += 1024) {
            const int4 v = *(const int4*)(cnt + i);
            s += v.x + v.y + v.z + v.w;
        }
        red[t] = s;
        __syncthreads();
        #pragma unroll
        for (int d = 128; d > 0; d >>= 1) {
            if (t < d) red[t] += red[t + d];
            __syncthreads();
        }
        const int base = red[0];
        __syncthreads();
        // own chunk scan (NN%4==0 so idx<NN implies idx+3<NN)
        const int idx = b * 1024 + t * 4;
        int4 v = make_int4(0, 0, 0, 0);
        if (idx < NN) v = *(const int4*)(cnt + idx);
        const int sl = v.x + v.y + v.z + v.w;
        red[t] = sl;
        __syncthreads();
        for (int d = 1; d < 256; d <<= 1) {
            const int u = (t >= d) ? red[t - d] : 0;
            __syncthreads();
            red[t] += u;
            __syncthreads();
        }
        if (idx < NN) {
            const int e0 = base + red[t] - sl;
            const int4 o = make_int4(e0, e0 + v.x, e0 + v.x + v.y,
                                     e0 + v.x + v.y + v.z);
            *(int4*)(off + idx) = o;
            *(int4*)(cur + idx) = o;    // atomic cursors for scatter
        }
    }
}

// ---------------- K4: scatter — atomic-cursor direct CSR fill ----------------
// esrc order within a node is nondeterministic (atomics) — sums are commutative,
// and the prior 2-level build was equally nondeterministic.
__global__ __launch_bounds__(256) void scatter_kernel(const int* __restrict__ src,
                                                      const int* __restrict__ dst,
                                                      int* __restrict__ cur,
                                                      int* __restrict__ esrc) {
    const int stride = SCAT_BLOCKS * 256;
    for (int i = blockIdx.x * 256 + threadIdx.x; i < NE / 4; i += stride) {
        const int4 d = ((const int4*)dst)[i];
        const int4 s = ((const int4*)src)[i];
        int p;
        p = atomicAdd(&cur[d.x], 1); esrc[p] = s.x;
        p = atomicAdd(&cur[d.y], 1); esrc[p] = s.y;
        p = atomicAdd(&cur[d.z], 1); esrc[p] = s.z;
        p = atomicAdd(&cur[d.w], 1); esrc[p] = s.w;
    }
}

// ---------------- Agg1 (R8 version): agg[n](bf16) = relu(sum h1[src_e]), d=128 --------
// Half-wave per edge (32 lanes x ushort4 = one 256B row); unroll 4 -> 8 loads in flight.
// [R12/R15 analysis: at its L3-random-fill roofline (~178MB L2-fill @ ~3.1 TB/s random
//  256B granules; h1 fits L3 so FETCH is L3 traffic, not HBM). bf16-DONE.]
__global__ __launch_bounds__(256) void agg1_kernel(const __bf16* __restrict__ h1,
                                                   const int* __restrict__ esrc,
                                                   const int* __restrict__ off,
                                                   __bf16* __restrict__ agg) {
    const int w = (blockIdx.x * 256 + threadIdx.x) >> 6;
    if (w >= NN) return;
    const int lane = threadIdx.x & 63;
    const int half = lane >> 5;
    const int c = (lane & 31) * 4;
    const int b = off[w], e = off[w + 1];
    float4 a0 = make_float4(0.f, 0.f, 0.f, 0.f);
    float4 a1 = a0, a2 = a0, a3 = a0;
    int j = b + half;
    for (; j + 6 < e; j += 8) {
        const int s0 = esrc[j], s1 = esrc[j + 2], s2 = esrc[j + 4], s3 = esrc[j + 6];
        acc4(a0, bf4_to_f4(*(const ushort4*)(h1 + (size_t)s0 * DH + c)));
        acc4(a1, bf4_to_f4(*(const ushort4*)(h1 + (size_t)s1 * DH + c)));
        acc4(a2, bf4_to_f4(*(const ushort4*)(h1 + (size_t)s2 * DH + c)));
        acc4(a3, bf4_to_f4(*(const ushort4*)(h1 + (size_t)s3 * DH + c)));
    }
    for (; j < e; j += 2) {
        const int s = esrc[j];
        acc4(a0, bf4_to_f4(*(const ushort4*)(h1 + (size_t)s * DH + c)));
    }
    float4 acc = make_float4(a0.x + a1.x + a2.x + a3.x,
                             a0.y + a1.y + a2.y + a3.y,
                             a0.z + a1.z + a2.z + a3.z,
                             a0.w + a1.w + a2.w + a3.w);
    acc.x += __shfl_xor(acc.x, 32);
    acc.y += __shfl_xor(acc.y, 32);
    acc.z += __shfl_xor(acc.z, 32);
    acc.w += __shfl_xor(acc.w, 32);
    if (half == 0) {
        ushort4 o;
        o.x = f2bf(fmaxf(acc.x, 0.f));
        o.y = f2bf(fmaxf(acc.y, 0.f));
        o.z = f2bf(fmaxf(acc.z, 0.f));
        o.w = f2bf(fmaxf(acc.w, 0.f));
        *(ushort4*)(agg + (size_t)w * DH + c) = o;
    }
}

// ---------------- GEMM2 (bf16 MFMA, no LDS, no barriers) ----------------
__global__ __launch_bounds__(256) void gemm2_kernel(const __bf16* __restrict__ agg,
                                                    const __bf16* __restrict__ Wf2,
                                                    __bf16* __restrict__ h2) {
    const int t = threadIdx.x;
    const int wave = t >> 6, lane = t & 63;
    const int q = lane >> 4, m = lane & 15;
    const int row0 = blockIdx.x * 64 + wave * 16;
    const int r = row0 + m;
    const bool ok = r < NN;
    const __bf16* ap = agg + (size_t)r * DH;

    f32x4 acc[3];
    #pragma unroll
    for (int nt = 0; nt < 3; ++nt)
        #pragma unroll
        for (int rr = 0; rr < 4; ++rr) acc[nt][rr] = 0.f;

    const bf16x8* wf2 = (const bf16x8*)Wf2;
    #pragma unroll
    for (int ks = 0; ks < 4; ++ks) {
        const int k0 = ks * 32 + q * 8;
        const bf16x8 a = ok ? *(const bf16x8*)(ap + k0) : bf16x8_zero();
        #pragma unroll
        for (int nt = 0; nt < 3; ++nt) {
            const bf16x8 b = wf2[(ks * 3 + nt) * 64 + lane];
            acc[nt] = __builtin_amdgcn_mfma_f32_16x16x32_bf16(a, b, acc[nt], 0, 0, 0);
        }
    }
    #pragma unroll
    for (int reg = 0; reg < 4; ++reg) {
        const int rr = row0 + q * 4 + reg;
        if (rr < NN) {
            #pragma unroll
            for (int nt = 0; nt < 3; ++nt) {
                const int cc = nt * 16 + m;
                if (cc < DO) h2[(size_t)rr * DO + cc] = (__bf16)acc[nt][reg];
            }
        }
    }
}

// ---------------- Agg2 (R11 version): out[n](f32) = sum h2[src_e], d=40 ---------------
// Index-broadcast with uniform-exec shuffles (clamped sources, predicated adds).
__global__ __launch_bounds__(256) void agg2_kernel(const __bf16* __restrict__ h2,
                                                   const int* __restrict__ esrc,
                                                   const int* __restrict__ off,
                                                   float* __restrict__ out) {
    const int w = (blockIdx.x * 256 + threadIdx.x) >> 6;
    if (w >= NN) return;
    const int lane = threadIdx.x & 63;
    const int sub = lane / 10;          // 0..5 active, 6 for lanes 60..63
    const int c = (lane % 10) * 4;
    const int b = off[w], e = off[w + 1];
    const int deg = e - b;
    float4 a0 = make_float4(0.f, 0.f, 0.f, 0.f);
    float4 a1 = a0, a2 = a0, a3 = a0;

    for (int base = 0; base < deg; base += 64) {
        const int cnt = min(64, deg - base);          // wave-uniform
        const int cl = cnt - 1;
        const int idx = (base + lane < deg) ? esrc[b + base + lane] : 0;
        const bool act = sub < 6;
        int kk = 0;
        for (; kk + 24 <= cnt; kk += 24) {            // uniform: 4 edges/sub
            const int e0 = kk + sub;
            const int s0 = __shfl(idx, min(e0, cl));
            const int s1 = __shfl(idx, min(e0 + 6, cl));
            const int s2 = __shfl(idx, min(e0 + 12, cl));
            const int s3 = __shfl(idx, min(e0 + 18, cl));
            const float4 v0 = bf4_to_f4(*(const ushort4*)(h2 + (size_t)s0 * DO + c));
            const float4 v1 = bf4_to_f4(*(const ushort4*)(h2 + (size_t)s1 * DO + c));
            const float4 v2 = bf4_to_f4(*(const ushort4*)(h2 + (size_t)s2 * DO + c));
            const float4 v3 = bf4_to_f4(*(const ushort4*)(h2 + (size_t)s3 * DO + c));
            if (act) { acc4(a0, v0); acc4(a1, v1); acc4(a2, v2); acc4(a3, v3); }
        }
        for (; kk + 12 <= cnt; kk += 12) {            // uniform: 2 edges/sub
            const int e0 = kk + sub;
            const int s0 = __shfl(idx, min(e0, cl));
            const int s1 = __shfl(idx, min(e0 + 6, cl));
            const float4 v0 = bf4_to_f4(*(const ushort4*)(h2 + (size_t)s0 * DO + c));
            const float4 v1 = bf4_to_f4(*(const ushort4*)(h2 + (size_t)s1 * DO + c));
            if (act) { acc4(a0, v0); acc4(a1, v1); }
        }
        for (; kk < cnt; kk += 6) {                   // uniform bound; clamp + predicate
            const int e0 = kk + sub;
            const int s0 = __shfl(idx, min(e0, cl));
            const float4 v = bf4_to_f4(*(const ushort4*)(h2 + (size_t)s0 * DO + c));
            if (act && e0 < cnt) acc4(a0, v);
        }
    }
    float4 acc = make_float4(a0.x + a1.x + a2.x + a3.x, a0.y + a1.y + a2.y + a3.y,
                             a0.z + a1.z + a2.z + a3.z, a0.w + a1.w + a2.w + a3.w);
    acc.x += __shfl(acc.x, lane + 30);
    acc.y += __shfl(acc.y, lane + 30);
    acc.z += __shfl(acc.z, lane + 30);
    acc.w += __shfl(acc.w, lane + 30);
    const float ax = acc.x + __shfl(acc.x, lane + 10) + __shfl(acc.x, lane + 20);
    const float ay = acc.y + __shfl(acc.y, lane + 10) + __shfl(acc.y, lane + 20);
    const float az = acc.z + __shfl(acc.z, lane + 10) + __shfl(acc.z, lane + 20);
    const float aw = acc.w + __shfl(acc.w, lane + 10) + __shfl(acc.w, lane + 20);
    if (lane < 10) {
        *(float4*)(out + (size_t)w * DO + c) = make_float4(ax, ay, az, aw);
    }
}

extern "C" void kernel_launch(void* const* d_in, const int* in_sizes, int n_in,
                              void* d_out, int out_size, void* d_ws, size_t ws_size,
                              hipStream_t stream) {
    const float* x  = (const float*)d_in[0];
    const int*   ei = (const int*)d_in[1];
    const float* W1 = (const float*)d_in[2];
    const float* W2 = (const float*)d_in[3];
    const int* src = ei;
    const int* dst = ei + NE;

    __bf16* Wf  = (__bf16*)d_ws;                     // 32768 bf16 = 64 KB
    __bf16* Wf2 = Wf + 32768;                        // 6144 bf16 = 12 KB
    __bf16* h1  = Wf2 + 6144;                        // NN*128 bf16 = 25.6 MB
    __bf16* agg = h1 + (size_t)NN * DH;              // NN*128 bf16 = 25.6 MB
    __bf16* h2  = h1;                                // NN*40 bf16 (aliases h1; dead after agg1)
    int* esrc   = (int*)(agg + (size_t)NN * DH);     // NE
    int* off    = esrc + NE;                         // NN+1
    int* cnt    = off + NN + 1;                      // NN
    int* cur    = cnt + NN;                          // NN

    float* out = (float*)d_out;

    wpack_zero_kernel<<<WPACK_BLOCKS + ZERO_BLOCKS, 256, 0, stream>>>(
        W1, W2, Wf, Wf2, cnt, off);
    hist_kernel<<<HIST_BLOCKS, 256, 0, stream>>>(dst, cnt);
    gemm1_scan_kernel<<<GEMM1_BLOCKS + NBS2, 256, 0, stream>>>(
        x, Wf, h1, cnt, off, cur);
    scatter_kernel<<<SCAT_BLOCKS, 256, 0, stream>>>(src, dst, cur, esrc);
    agg1_kernel<<<(NN * 64 + 255) / 256, 256, 0, stream>>>(h1, esrc, off, agg);
    gemm2_kernel<<<(NN + 63) / 64, 256, 0, stream>>>(agg, Wf2, h2);
    agg2_kernel<<<(NN * 64 + 255) / 256, 256, 0, stream>>>(h2, esrc, off, out);
}

// Round 12
// 329.507 us; speedup vs baseline: 1.3586x; 1.3586x over previous
//
#include <hip/hip_runtime.h>

constexpr int NN = 100000;   // nodes
constexpr int NE = 1600000;  // edges
constexpr int DI = 256, DH = 128, DO = 40;

// Bucket radix sort params (R14 structure, measured 335.7us best)
// [R17 FAILED: 1-level CSR build -> scatter_kernel 107us. Scattered 4B esrc stores
//  cost 16x write amplification (WRITE_SIZE 107MB ~= 1.6M x 64B lines @ ~1 TB/s).
//  LESSON: scattered 4B global writes are 16x amplified; stage through LDS (the
//  2-level bucket build's sort does exactly this). Reverted.]
// [R15 FAILED: merged chain+gemm1 paid max(LDS) across branches, occupancy collapse.]
constexpr int NB = (NN + 255) >> 8;        // 391 buckets of 256 dst values
constexpr int NB_BLK = 512;                // blocks in hist/scatter passes
constexpr int CHUNK = NE / NB_BLK;         // 3125 edges per block (exact)
constexpr int M2 = NB * NB_BLK;            // 200192 hist entries
constexpr int NBS = (M2 + 1023) / 1024;    // 196 scan blocks
constexpr int STAGE_CAP = 6144;            // bucket staging (avg load ~4092)
constexpr int WPACK_BLOCKS = 152;          // 128 (W1) + 24 (W2)
constexpr int GEMM1_BLOCKS = (NN + 63) / 64;   // 1563

typedef __attribute__((ext_vector_type(8))) __bf16 bf16x8;
typedef __attribute__((ext_vector_type(4))) float f32x4;

__device__ inline float4 bf4_to_f4(ushort4 u) {
    return make_float4(__builtin_bit_cast(float, (unsigned)u.x << 16),
                       __builtin_bit_cast(float, (unsigned)u.y << 16),
                       __builtin_bit_cast(float, (unsigned)u.z << 16),
                       __builtin_bit_cast(float, (unsigned)u.w << 16));
}
__device__ inline unsigned short f2bf(float f) {
    return __builtin_bit_cast(unsigned short, (__bf16)f);   // RNE
}
__device__ inline bf16x8 bf16x8_zero() {
    bf16x8 r;
    #pragma unroll
    for (int j = 0; j < 8; ++j) r[j] = (__bf16)0.f;
    return r;
}
__device__ inline bf16x8 load_cvt_a(const float* __restrict__ p, bool ok) {
    if (!ok) return bf16x8_zero();
    bf16x8 r;
    const float4 v0 = *(const float4*)p;
    const float4 v1 = *(const float4*)(p + 4);
    r[0] = (__bf16)v0.x; r[1] = (__bf16)v0.y; r[2] = (__bf16)v0.z; r[3] = (__bf16)v0.w;
    r[4] = (__bf16)v1.x; r[5] = (__bf16)v1.y; r[6] = (__bf16)v1.z; r[7] = (__bf16)v1.w;
    return r;
}
__device__ inline void acc4(float4& a, float4 v) {
    a.x += v.x; a.y += v.y; a.z += v.z; a.w += v.w;
}

// ---------------- K1: wpack (blocks 0..151)  ||  bucket histogram (152..663) -------
__global__ __launch_bounds__(256) void wpack_hist_kernel(const float* __restrict__ W1,
                                                         const float* __restrict__ W2,
                                                         const int* __restrict__ dst,
                                                         __bf16* __restrict__ Wf,
                                                         __bf16* __restrict__ Wf2,
                                                         int* __restrict__ hist2d) {
    __shared__ int h[NB];
    if (blockIdx.x < 128) {
        const int i = blockIdx.x * 256 + threadIdx.x;   // 32768 total
        const int j = i & 7;
        const int lane = (i >> 3) & 63;
        const int nt = (i >> 9) & 7;
        const int kt = i >> 12;
        const int k = kt * 32 + (lane >> 4) * 8 + j;
        const int n = nt * 16 + (lane & 15);
        Wf[i] = (__bf16)W1[(size_t)k * DH + n];
    } else if (blockIdx.x < WPACK_BLOCKS) {
        const int i = (blockIdx.x - 128) * 256 + threadIdx.x;   // 6144 total
        if (i < 6144) {
            const int j = i & 7;
            const int lane = (i >> 3) & 63;
            const int g = i >> 9;          // 0..11
            const int nt = g % 3, ks = g / 3;
            const int k = ks * 32 + (lane >> 4) * 8 + j;
            const int n = nt * 16 + (lane & 15);
            Wf2[i] = (n < DO) ? (__bf16)W2[(size_t)k * DO + n] : (__bf16)0.f;
        }
    } else {
        const int hb = blockIdx.x - WPACK_BLOCKS;       // 0..NB_BLK-1
        for (int i = threadIdx.x; i < NB; i += 256) h[i] = 0;
        __syncthreads();
        const int base = hb * CHUNK;
        for (int i = threadIdx.x; i < CHUNK; i += 256)
            atomicAdd(&h[dst[base + i] >> 8], 1);
        __syncthreads();
        for (int i = threadIdx.x; i < NB; i += 256)
            hist2d[i * NB_BLK + hb] = h[i];             // bucket-major
    }
}

// ---------------- K2: scan (blocks 0..NBS-1)  ||  gemm1 (NBS..NBS+1562) -----
// [R14] Scan blocks FIRST (scan-last made a +20us serial tail behind gemm1).
// [R14] Wf staged in LDS: gemm1 was latency-bound (MfmaUtil 2.9%, occ 33%)
// streaming the 64KB Wf table from L2 per wave. ds_read_b128 fixed it (82->~30us).
__global__ __launch_bounds__(256) void gemm1_scan_kernel(const float* __restrict__ x,
                                                         const __bf16* __restrict__ Wf,
                                                         __bf16* __restrict__ h1,
                                                         const int* __restrict__ hist2d,
                                                         int* __restrict__ offs2d) {
    __shared__ __bf16 wlds[32768];   // 64 KB: Wf copy (gemm1) / scan scratch (scan)
    if (blockIdx.x >= NBS) {
        const int t = threadIdx.x;
        const int wave = t >> 6, lane = t & 63;
        const int q = lane >> 4, m = lane & 15;
        const int row0 = (blockIdx.x - NBS) * 64 + wave * 16;
        const int r = row0 + m;
        const bool ok = r < NN;
        const float* xp = x + (size_t)r * DI;

        bf16x8 a[8];
        #pragma unroll
        for (int kt = 0; kt < 8; ++kt)
            a[kt] = load_cvt_a(xp + kt * 32 + q * 8, ok);

        // Stage Wf (64 KB) into LDS: 16 coalesced 4KB steps.
        bf16x8* wl = (bf16x8*)wlds;
        const bf16x8* wfv = (const bf16x8*)Wf;
        #pragma unroll
        for (int i = 0; i < 16; ++i)
            wl[t + i * 256] = wfv[t + i * 256];

        f32x4 acc[8];
        #pragma unroll
        for (int nt = 0; nt < 8; ++nt)
            #pragma unroll
            for (int rr = 0; rr < 4; ++rr) acc[nt][rr] = 0.f;

        __syncthreads();

        #pragma unroll
        for (int kt = 0; kt < 8; ++kt) {
            #pragma unroll
            for (int nt = 0; nt < 8; ++nt) {
                const bf16x8 b = wl[(kt * 8 + nt) * 64 + lane];   // ds_read_b128
                acc[nt] = __builtin_amdgcn_mfma_f32_16x16x32_bf16(a[kt], b, acc[nt], 0, 0, 0);
            }
        }
        #pragma unroll
        for (int reg = 0; reg < 4; ++reg) {
            const int rr = row0 + q * 4 + reg;
            if (rr < NN) {
                __bf16* hp = h1 + (size_t)rr * DH + m;
                #pragma unroll
                for (int nt = 0; nt < 8; ++nt) hp[nt * 16] = (__bf16)acc[nt][reg];
            }
        }
    } else {
        int* red = (int*)wlds;                      // overlay scan scratch in LDS
        const int b = blockIdx.x;                   // 0..NBS-1
        const int t = threadIdx.x;
        // prefix base = sum of hist2d[0 .. b*1024)
        int s = 0;
        const int limit = b * 1024;
        for (int i = t * 4; i < limit; i += 1024) {
            const int4 v = *(const int4*)(hist2d + i);
            s += v.x + v.y + v.z + v.w;
        }
        red[t] = s;
        __syncthreads();
        #pragma unroll
        for (int d = 128; d > 0; d >>= 1) {
            if (t < d) red[t] += red[t + d];
            __syncthreads();
        }
        const int base = red[0];
        __syncthreads();
        // own chunk scan
        const int idx = b * 1024 + t * 4;
        int4 v = make_int4(0, 0, 0, 0);
        if (idx < M2) v = *(const int4*)(hist2d + idx);
        const int sl = v.x + v.y + v.z + v.w;
        red[t] = sl;
        __syncthreads();
        for (int d = 1; d < 256; d <<= 1) {
            const int u = (t >= d) ? red[t - d] : 0;
            __syncthreads();
            red[t] += u;
            __syncthreads();
        }
        if (idx < M2) {
            const int e0 = base + red[t] - sl;
            *(int4*)(offs2d + idx) = make_int4(e0, e0 + v.x, e0 + v.x + v.y,
                                               e0 + v.x + v.y + v.z);
        }
    }
}

// ---------------- P3: scatter packed (src | dstbyte<<24) into bucket partitions -------
__global__ __launch_bounds__(256) void bucket_scatter_kernel(const int* __restrict__ src,
                                                             const int* __restrict__ dst,
                                                             const int* __restrict__ offs2d,
                                                             unsigned* __restrict__ epack) {
    __shared__ int cur[NB];
    for (int i = threadIdx.x; i < NB; i += 256)
        cur[i] = offs2d[i * NB_BLK + blockIdx.x];
    __syncthreads();
    const int base = blockIdx.x * CHUNK;
    for (int i = threadIdx.x; i < CHUNK; i += 256) {
        const int d = dst[base + i], s = src[base + i];
        const int p = atomicAdd(&cur[d >> 8], 1);
        epack[p] = (unsigned)s | ((unsigned)(d & 255) << 24);
    }
}

// ---------------- P4: within-bucket counting sort; emits off[] and esrc ----------------
__global__ __launch_bounds__(256) void bucket_sort_kernel(const unsigned* __restrict__ epack,
                                                          const int* __restrict__ offs2d,
                                                          int* __restrict__ off,
                                                          int* __restrict__ esrc) {
    __shared__ int cnt[256];
    __shared__ int incl[256];
    __shared__ int cur[256];
    __shared__ int stage[STAGE_CAP];
    const int b = blockIdx.x;
    const int t = threadIdx.x;
    const int bstart = offs2d[b * NB_BLK];
    const int bend = (b + 1 < NB) ? offs2d[(b + 1) * NB_BLK] : NE;
    const int n = bend - bstart;
    cnt[t] = 0;
    __syncthreads();
    for (int i = t; i < n; i += 256)
        atomicAdd(&cnt[epack[bstart + i] >> 24], 1);
    __syncthreads();
    incl[t] = cnt[t];
    __syncthreads();
    for (int d = 1; d < 256; d <<= 1) {
        const int u = (t >= d) ? incl[t - d] : 0;
        __syncthreads();
        incl[t] += u;
        __syncthreads();
    }
    const int ex = incl[t] - cnt[t];   // exclusive prefix within bucket
    const int node = (b << 8) + t;
    if (node <= NN) off[node] = bstart + ex;   // node==NN -> off[NN]=NE
    cur[t] = ex;
    __syncthreads();
    const bool staged = (n <= STAGE_CAP);
    for (int i = t; i < n; i += 256) {
        const unsigned pk = epack[bstart + i];
        const int p = atomicAdd(&cur[pk >> 24], 1);
        const int s = (int)(pk & 0xFFFFFFu);
        if (staged) stage[p] = s;
        else esrc[bstart + p] = s;
    }
    __syncthreads();
    if (staged)
        for (int i = t; i < n; i += 256) esrc[bstart + i] = stage[i];
}

// ---------------- Agg1+GEMM2 fused [R18]: h2[n] = relu(sum h1[src_e]) @ W2 ----------
// Block = 16 nodes (NN/16 = 6250 exact). Each of 4 waves aggregates 4 nodes serially
// with the proven R8 half-wave gather (8 loads in flight -> per-wave MLP unchanged;
// 25k waves is ample TLP). Relu'd rows -> LDS [16][136] (272B stride: 16B-aligned
// bf16x8 reads, at LDS throughput floor). Waves 0..2 then run the exact gemm2 MFMA
// (same Wf2 packing). Deletes agg buffer (25.6MB W + 25.6MB R) and gemm2 launch.
// h2 must NOT alias h1 (same-kernel race) -> separate 8MB buffer.
__global__ __launch_bounds__(256) void agg1g2_kernel(const __bf16* __restrict__ h1,
                                                     const int* __restrict__ esrc,
                                                     const int* __restrict__ off,
                                                     const __bf16* __restrict__ Wf2,
                                                     __bf16* __restrict__ h2) {
    __shared__ __bf16 rows[16][136];
    const int t = threadIdx.x;
    const int wave = t >> 6, lane = t & 63;
    const int half = lane >> 5;
    const int c = (lane & 31) * 4;
    const int node0 = blockIdx.x * 16;

    for (int k = 0; k < 4; ++k) {
        const int r = wave * 4 + k;
        const int w = node0 + r;
        const int b = off[w], e = off[w + 1];
        float4 a0 = make_float4(0.f, 0.f, 0.f, 0.f);
        float4 a1 = a0, a2 = a0, a3 = a0;
        int j = b + half;
        for (; j + 6 < e; j += 8) {
            const int s0 = esrc[j], s1 = esrc[j + 2], s2 = esrc[j + 4], s3 = esrc[j + 6];
            acc4(a0, bf4_to_f4(*(const ushort4*)(h1 + (size_t)s0 * DH + c)));
            acc4(a1, bf4_to_f4(*(const ushort4*)(h1 + (size_t)s1 * DH + c)));
            acc4(a2, bf4_to_f4(*(const ushort4*)(h1 + (size_t)s2 * DH + c)));
            acc4(a3, bf4_to_f4(*(const ushort4*)(h1 + (size_t)s3 * DH + c)));
        }
        for (; j < e; j += 2) {
            const int s = esrc[j];
            acc4(a0, bf4_to_f4(*(const ushort4*)(h1 + (size_t)s * DH + c)));
        }
        float4 acc = make_float4(a0.x + a1.x + a2.x + a3.x,
                                 a0.y + a1.y + a2.y + a3.y,
                                 a0.z + a1.z + a2.z + a3.z,
                                 a0.w + a1.w + a2.w + a3.w);
        acc.x += __shfl_xor(acc.x, 32);
        acc.y += __shfl_xor(acc.y, 32);
        acc.z += __shfl_xor(acc.z, 32);
        acc.w += __shfl_xor(acc.w, 32);
        if (half == 0) {
            ushort4 o;
            o.x = f2bf(fmaxf(acc.x, 0.f));
            o.y = f2bf(fmaxf(acc.y, 0.f));
            o.z = f2bf(fmaxf(acc.z, 0.f));
            o.w = f2bf(fmaxf(acc.w, 0.f));
            *(ushort4*)(&rows[r][c]) = o;
        }
    }
    __syncthreads();

    if (wave < 3) {                       // wave == nt (output 16-col slab)
        const int nt = wave;
        const int q = lane >> 4, m = lane & 15;
        f32x4 acc;
        #pragma unroll
        for (int rr = 0; rr < 4; ++rr) acc[rr] = 0.f;
        const bf16x8* wf2 = (const bf16x8*)Wf2;
        #pragma unroll
        for (int ks = 0; ks < 4; ++ks) {
            const bf16x8 a = *(const bf16x8*)(&rows[m][ks * 32 + q * 8]);
            const bf16x8 b = wf2[(ks * 3 + nt) * 64 + lane];
            acc = __builtin_amdgcn_mfma_f32_16x16x32_bf16(a, b, acc, 0, 0, 0);
        }
        const int cc = nt * 16 + m;
        if (cc < DO) {
            #pragma unroll
            for (int reg = 0; reg < 4; ++reg) {
                const int rr = node0 + q * 4 + reg;
                h2[(size_t)rr * DO + cc] = (__bf16)acc[reg];
            }
        }
    }
}

// ---------------- Agg2 (R11 version): out[n](f32) = sum h2[src_e], d=40 ---------------
// Index-broadcast with uniform-exec shuffles (clamped sources, predicated adds).
__global__ __launch_bounds__(256) void agg2_kernel(const __bf16* __restrict__ h2,
                                                   const int* __restrict__ esrc,
                                                   const int* __restrict__ off,
                                                   float* __restrict__ out) {
    const int w = (blockIdx.x * 256 + threadIdx.x) >> 6;
    if (w >= NN) return;
    const int lane = threadIdx.x & 63;
    const int sub = lane / 10;          // 0..5 active, 6 for lanes 60..63
    const int c = (lane % 10) * 4;
    const int b = off[w], e = off[w + 1];
    const int deg = e - b;
    float4 a0 = make_float4(0.f, 0.f, 0.f, 0.f);
    float4 a1 = a0, a2 = a0, a3 = a0;

    for (int base = 0; base < deg; base += 64) {
        const int cnt = min(64, deg - base);          // wave-uniform
        const int cl = cnt - 1;
        const int idx = (base + lane < deg) ? esrc[b + base + lane] : 0;
        const bool act = sub < 6;
        int kk = 0;
        for (; kk + 24 <= cnt; kk += 24) {            // uniform: 4 edges/sub
            const int e0 = kk + sub;
            const int s0 = __shfl(idx, min(e0, cl));
            const int s1 = __shfl(idx, min(e0 + 6, cl));
            const int s2 = __shfl(idx, min(e0 + 12, cl));
            const int s3 = __shfl(idx, min(e0 + 18, cl));
            const float4 v0 = bf4_to_f4(*(const ushort4*)(h2 + (size_t)s0 * DO + c));
            const float4 v1 = bf4_to_f4(*(const ushort4*)(h2 + (size_t)s1 * DO + c));
            const float4 v2 = bf4_to_f4(*(const ushort4*)(h2 + (size_t)s2 * DO + c));
            const float4 v3 = bf4_to_f4(*(const ushort4*)(h2 + (size_t)s3 * DO + c));
            if (act) { acc4(a0, v0); acc4(a1, v1); acc4(a2, v2); acc4(a3, v3); }
        }
        for (; kk + 12 <= cnt; kk += 12) {            // uniform: 2 edges/sub
            const int e0 = kk + sub;
            const int s0 = __shfl(idx, min(e0, cl));
            const int s1 = __shfl(idx, min(e0 + 6, cl));
            const float4 v0 = bf4_to_f4(*(const ushort4*)(h2 + (size_t)s0 * DO + c));
            const float4 v1 = bf4_to_f4(*(const ushort4*)(h2 + (size_t)s1 * DO + c));
            if (act) { acc4(a0, v0); acc4(a1, v1); }
        }
        for (; kk < cnt; kk += 6) {                   // uniform bound; clamp + predicate
            const int e0 = kk + sub;
            const int s0 = __shfl(idx, min(e0, cl));
            const float4 v = bf4_to_f4(*(const ushort4*)(h2 + (size_t)s0 * DO + c));
            if (act && e0 < cnt) acc4(a0, v);
        }
    }
    float4 acc = make_float4(a0.x + a1.x + a2.x + a3.x, a0.y + a1.y + a2.y + a3.y,
                             a0.z + a1.z + a2.z + a3.z, a0.w + a1.w + a2.w + a3.w);
    acc.x += __shfl(acc.x, lane + 30);
    acc.y += __shfl(acc.y, lane + 30);
    acc.z += __shfl(acc.z, lane + 30);
    acc.w += __shfl(acc.w, lane + 30);
    const float ax = acc.x + __shfl(acc.x, lane + 10) + __shfl(acc.x, lane + 20);
    const float ay = acc.y + __shfl(acc.y, lane + 10) + __shfl(acc.y, lane + 20);
    const float az = acc.z + __shfl(acc.z, lane + 10) + __shfl(acc.z, lane + 20);
    const float aw = acc.w + __shfl(acc.w, lane + 10) + __shfl(acc.w, lane + 20);
    if (lane < 10) {
        *(float4*)(out + (size_t)w * DO + c) = make_float4(ax, ay, az, aw);
    }
}

extern "C" void kernel_launch(void* const* d_in, const int* in_sizes, int n_in,
                              void* d_out, int out_size, void* d_ws, size_t ws_size,
                              hipStream_t stream) {
    const float* x  = (const float*)d_in[0];
    const int*   ei = (const int*)d_in[1];
    const float* W1 = (const float*)d_in[2];
    const float* W2 = (const float*)d_in[3];
    const int* src = ei;
    const int* dst = ei + NE;

    __bf16* Wf  = (__bf16*)d_ws;                     // 32768 bf16 = 64 KB
    __bf16* Wf2 = Wf + 32768;                        // 6144 bf16 = 12 KB
    __bf16* h1  = Wf2 + 6144;                        // NN*128 bf16 = 25.6 MB
    __bf16* h2  = h1 + (size_t)NN * DH;              // NN*40 bf16 = 8 MB (no alias: fused kernel)
    unsigned* epack = (unsigned*)(h2 + (size_t)NN * DO);   // NE uint = 6.4 MB
    int* esrc   = (int*)(epack + NE);                // NE
    int* off    = esrc + NE;                         // NN+1
    int* hist2d = off + NN + 1;                      // M2
    int* offs2d = hist2d + M2;                       // M2

    float* out = (float*)d_out;

    wpack_hist_kernel<<<WPACK_BLOCKS + NB_BLK, 256, 0, stream>>>(W1, W2, dst, Wf, Wf2, hist2d);
    gemm1_scan_kernel<<<GEMM1_BLOCKS + NBS, 256, 0, stream>>>(x, Wf, h1, hist2d, offs2d);
    bucket_scatter_kernel<<<NB_BLK, 256, 0, stream>>>(src, dst, offs2d, epack);
    bucket_sort_kernel<<<NB, 256, 0, stream>>>(epack, offs2d, off, esrc);
    agg1g2_kernel<<<NN / 16, 256, 0, stream>>>(h1, esrc, off, Wf2, h2);
    agg2_kernel<<<(NN * 64 + 255) / 256, 256, 0, stream>>>(h2, esrc, off, out);
}